// Round 1
// 1501.029 us; speedup vs baseline: 1.0177x; 1.0177x over previous
//
#include <hip/hip_runtime.h>
#include <hip/hip_bf16.h>
#include <cstdint>
#include <cstddef>

// Sizes: B=64, S=128, T=32, H=512, E=512, VOC=32000, A=2H=1024. All I/O fp32.
typedef unsigned short u16;
typedef __attribute__((ext_vector_type(8))) short s16x8;   // 8 bf16 (MFMA A/B frag)
typedef __attribute__((ext_vector_type(4))) float f32x4;   // MFMA acc
typedef __attribute__((ext_vector_type(4))) unsigned short u16x4;

__device__ __forceinline__ float b2f(u16 u){ unsigned int i = ((unsigned int)u)<<16; float f; __builtin_memcpy(&f,&i,4); return f; }
__device__ __forceinline__ u16 f2b(float f){ unsigned int i; __builtin_memcpy(&i,&f,4); i = (i + 0x7fffu + ((i>>16)&1u))>>16; return (u16)i; }
__device__ __forceinline__ float tanh_f(float x){ return 1.f - 2.f/(1.f + __expf(2.f*x)); } // inf-safe
__device__ __forceinline__ float sig_f(float x){ return 1.f/(1.f + __expf(-x)); }

__device__ __forceinline__ void cp16(const u16* g, u16* l) {
  // async global->LDS: LDS dest = wave-uniform base + lane*16B
  __builtin_amdgcn_global_load_lds((const __attribute__((address_space(1))) unsigned int*)g,
                                   (__attribute__((address_space(3))) unsigned int*)l, 16, 0, 0);
}

// ---------- fp32 -> bf16 bulk convert (n4 = n/4 float4 groups) ----------
__global__ void k_cvt(const float* __restrict__ src, u16* __restrict__ dst, int n4) {
  int i = blockIdx.x*256 + threadIdx.x;
  if (i >= n4) return;
  float4 v = ((const float4*)src)[i];
  u16x4 o; o.x = f2b(v.x); o.y = f2b(v.y); o.z = f2b(v.z); o.w = f2b(v.w);
  ((u16x4*)dst)[i] = o;
}

// ---------- C = A(M,K) @ B(N,K)^T (+bias1+bias2), bf16 in, f32/bf16 out ----------
// grid: (N/128, M/128, batch), 256 threads. M,N mult of 128; K mult of 32.
// swz=1: XCD-chunked, M-innermost block remap (requires nwg%8==0, gridDim.z==1).
__global__ __launch_bounds__(256, 2) void gemm_bt(
    const u16* __restrict__ A, const u16* __restrict__ B, void* __restrict__ Cv,
    const float* __restrict__ bias1, const float* __restrict__ bias2,
    int M, int N, int K, int ldA, int ldB, int ldC,
    long long strideA, long long strideB, long long strideC, int outBf16, int swz)
{
  __shared__ u16 As[128*32];
  __shared__ u16 Bs[128*32];
  const int bz = blockIdx.z;
  const u16* Ab = A + (size_t)bz*strideA;
  const u16* Bb = B + (size_t)bz*strideB;
  int bxx = blockIdx.x, byy = blockIdx.y;
  if (swz) {
    // linear dispatch id (x fastest); HW round-robins linear id across 8 XCDs.
    int nx = gridDim.x, ny = gridDim.y;
    int nwg = nx * ny;                 // must be multiple of 8 (vocab: 4000)
    int orig = byy * nx + bxx;
    int cpx = nwg >> 3;                // blocks per XCD chunk
    int id = (orig & 7) * cpx + (orig >> 3);   // chunked: XCD k owns [k*cpx, (k+1)*cpx)
    byy = id % ny;                     // M-tile innermost -> B panel stays in this XCD's L2
    bxx = id / ny;
  }
  const int tn = bxx * 128;
  const int tm = byy * 128;
  const int tid = threadIdx.x, wid = tid>>6, lane = tid&63;
  const int wm = wid & 1, wn = wid >> 1;
  const int lrow = lane & 15, lk = (lane>>4)*8;

  f32x4 acc[4][4];
  #pragma unroll
  for (int i=0;i<4;++i)
    #pragma unroll
    for (int j=0;j<4;++j) acc[i][j] = (f32x4){0.f,0.f,0.f,0.f};

  const int srow = lane>>2;
  const int scol = (lane&3)*8;

  for (int k0 = 0; k0 < K; k0 += 32) {
    int c0 = wid, c1 = wid + 4;
    cp16(Ab + (size_t)(tm + c0*16 + srow)*ldA + k0 + scol, As + c0*512);
    cp16(Ab + (size_t)(tm + c1*16 + srow)*ldA + k0 + scol, As + c1*512);
    cp16(Bb + (size_t)(tn + c0*16 + srow)*ldB + k0 + scol, Bs + c0*512);
    cp16(Bb + (size_t)(tn + c1*16 + srow)*ldB + k0 + scol, Bs + c1*512);
    __syncthreads();

    s16x8 af[4], bfr[4];
    #pragma unroll
    for (int mt=0; mt<4; ++mt)
      af[mt] = *(const s16x8*)(As + (size_t)(wm*64 + mt*16 + lrow)*32 + lk);
    #pragma unroll
    for (int nt=0; nt<4; ++nt)
      bfr[nt] = *(const s16x8*)(Bs + (size_t)(wn*64 + nt*16 + lrow)*32 + lk);
    #pragma unroll
    for (int mt=0; mt<4; ++mt)
      #pragma unroll
      for (int nt=0; nt<4; ++nt)
        acc[mt][nt] = __builtin_amdgcn_mfma_f32_16x16x32_bf16(af[mt], bfr[nt], acc[mt][nt], 0,0,0);
    __syncthreads();
  }

  float* Cf = (float*)Cv + (size_t)bz*strideC;
  u16*   Ch = (u16*)Cv + (size_t)bz*strideC;
  #pragma unroll
  for (int mt=0; mt<4; ++mt) {
    #pragma unroll
    for (int nt=0; nt<4; ++nt) {
      int col = tn + wn*64 + nt*16 + (lane&15);
      float badd = 0.f;
      if (bias1) badd += bias1[col];
      if (bias2) badd += bias2[col];
      #pragma unroll
      for (int r=0; r<4; ++r) {
        int row = tm + wm*64 + mt*16 + (lane>>4)*4 + r;
        float v = acc[mt][nt][r] + badd;
        if (outBf16) Ch[(size_t)row*ldC + col] = f2b(v);
        else         Cf[(size_t)row*ldC + col] = v;
      }
    }
  }
}

// ---------- vocab GEMM variant: A bf16 (cp16), B fp32 inline-converted ----------
__global__ __launch_bounds__(256, 2) void gemm_a16b32(
    const u16* __restrict__ A, const float* __restrict__ B, float* __restrict__ C,
    const float* __restrict__ bias, int M, int N, int K, int ldA, int ldB, int ldC, int swz)
{
  __shared__ u16 As[128*32];
  __shared__ u16 Bs[128*32];
  int bxx = blockIdx.x, byy = blockIdx.y;
  if (swz) {
    int nx = gridDim.x, ny = gridDim.y;
    int nwg = nx * ny;
    int orig = byy * nx + bxx;
    int cpx = nwg >> 3;
    int id = (orig & 7) * cpx + (orig >> 3);
    byy = id % ny;
    bxx = id / ny;
  }
  const int tn = bxx * 128;
  const int tm = byy * 128;
  const int tid = threadIdx.x, wid = tid>>6, lane = tid&63;
  const int wm = wid & 1, wn = wid >> 1;
  const int lrow = lane & 15, lk = (lane>>4)*8;

  f32x4 acc[4][4];
  #pragma unroll
  for (int i=0;i<4;++i)
    #pragma unroll
    for (int j=0;j<4;++j) acc[i][j] = (f32x4){0.f,0.f,0.f,0.f};

  const int srow = lane>>2;
  const int scol = (lane&3)*8;
  const int brow0 = tid>>3;        // 0..31
  const int bcol  = (tid&7)*4;     // 0..28

  for (int k0 = 0; k0 < K; k0 += 32) {
    int c0 = wid, c1 = wid + 4;
    cp16(A + (size_t)(tm + c0*16 + srow)*ldA + k0 + scol, As + c0*512);
    cp16(A + (size_t)(tm + c1*16 + srow)*ldA + k0 + scol, As + c1*512);
    #pragma unroll
    for (int rr=0; rr<4; ++rr) {
      int row = rr*32 + brow0;
      float4 v = *(const float4*)(B + (size_t)(tn + row)*ldB + k0 + bcol);
      u16x4 o; o.x = f2b(v.x); o.y = f2b(v.y); o.z = f2b(v.z); o.w = f2b(v.w);
      *(u16x4*)(Bs + (size_t)row*32 + bcol) = o;
    }
    __syncthreads();

    s16x8 af[4], bfr[4];
    #pragma unroll
    for (int mt=0; mt<4; ++mt)
      af[mt] = *(const s16x8*)(As + (size_t)(wm*64 + mt*16 + lrow)*32 + lk);
    #pragma unroll
    for (int nt=0; nt<4; ++nt)
      bfr[nt] = *(const s16x8*)(Bs + (size_t)(wn*64 + nt*16 + lrow)*32 + lk);
    #pragma unroll
    for (int mt=0; mt<4; ++mt)
      #pragma unroll
      for (int nt=0; nt<4; ++nt)
        acc[mt][nt] = __builtin_amdgcn_mfma_f32_16x16x32_bf16(af[mt], bfr[nt], acc[mt][nt], 0,0,0);
    __syncthreads();
  }

  #pragma unroll
  for (int mt=0; mt<4; ++mt) {
    #pragma unroll
    for (int nt=0; nt<4; ++nt) {
      int col = tn + wn*64 + nt*16 + (lane&15);
      float badd = bias ? bias[col] : 0.f;
      #pragma unroll
      for (int r=0; r<4; ++r) {
        int row = tm + wm*64 + mt*16 + (lane>>4)*4 + r;
        C[(size_t)row*ldC + col] = acc[mt][nt][r] + badd;
      }
    }
  }
}

// ---------- init: HSb[0]=bf16(hs0), CSb[0]=bf16(cs0), CS[0]=cs0 ----------
__global__ void k_init(const float* __restrict__ hs0, const float* __restrict__ cs0,
                       u16* __restrict__ HSb0, u16* __restrict__ CSb0, float* __restrict__ CS0) {
  int i = blockIdx.x*256 + threadIdx.x;   // 32768 total
  HSb0[i] = f2b(hs0[i]);
  float c = cs0[i];
  CSb0[i] = f2b(c);
  CS0[i] = c;
}

// ---------- X2[(t*64+b), e] = bf16(target[b, t, e]) ----------
__global__ void k_x2(const float* __restrict__ target, u16* __restrict__ X2) {
  int r = blockIdx.x;               // 0..2047
  int t = r >> 6, b = r & 63;
  float4 v = ((const float4*)(target + ((size_t)b*32 + t)*512))[threadIdx.x]; // 128 thr
  u16x4 o; o.x = f2b(v.x); o.y = f2b(v.y); o.z = f2b(v.z); o.w = f2b(v.w);
  *(u16x4*)(X2 + (size_t)r*512 + threadIdx.x*4) = o;
}

// ---------- EBt[b][s][c] = bf16(enc_flat[b][c*128 + s]) ----------
__global__ void k_ebt(const float* __restrict__ enc, u16* __restrict__ EBt) {
  __shared__ u16 tile[64][72];
  int b = blockIdx.z;
  int c0 = blockIdx.x*64, s0 = blockIdx.y*64;
  int tid = threadIdx.x;
  int j = tid & 63, i0 = tid >> 6;
  const float* src = enc + (size_t)b*131072;
  for (int i = i0; i < 64; i += 4)
    tile[i][j] = f2b(src[(size_t)(c0+i)*128 + (s0+j)]);
  __syncthreads();
  u16* dst = EBt + (size_t)b*131072;
  for (int i = i0; i < 64; i += 4)
    dst[(size_t)(s0+i)*1024 + (c0+j)] = tile[j][i];
}

// ---------- one LSTM step ----------
__global__ __launch_bounds__(256, 1) void lstm_step(
    const u16* __restrict__ HSb_t, const float* __restrict__ CS_t,
    const u16* __restrict__ Whh, const float* __restrict__ Xg_t,
    u16* __restrict__ HSb_n, float* __restrict__ CS_n, u16* __restrict__ CSb_n)
{
  int tid = threadIdx.x, wid = tid>>6, lane = tid&63;
  int hc = blockIdx.x * 16;
  int lr = lane & 15, lk = (lane>>4)*8;
  f32x4 acc[4];
  #pragma unroll
  for (int q=0;q<4;++q) acc[q] = (f32x4){0.f,0.f,0.f,0.f};
  int brow = wid*16 + lr;
  #pragma unroll
  for (int k0 = 0; k0 < 512; k0 += 32) {
    s16x8 a = *(const s16x8*)(HSb_t + (size_t)brow*512 + k0 + lk);
    #pragma unroll
    for (int q=0;q<4;++q) {
      int gj = q*512 + hc + lr;
      s16x8 bb = *(const s16x8*)(Whh + (size_t)gj*512 + k0 + lk);
      acc[q] = __builtin_amdgcn_mfma_f32_16x16x32_bf16(a, bb, acc[q], 0,0,0);
    }
  }
  int h = hc + lr;
  #pragma unroll
  for (int r=0;r<4;++r) {
    int b = wid*16 + (lane>>4)*4 + r;
    float gi = acc[0][r] + Xg_t[(size_t)b*2048 + h];
    float gf = acc[1][r] + Xg_t[(size_t)b*2048 + 512 + h];
    float gg = acc[2][r] + Xg_t[(size_t)b*2048 + 1024 + h];
    float go = acc[3][r] + Xg_t[(size_t)b*2048 + 1536 + h];
    float cs = CS_t[(size_t)b*512 + h];
    float csn = sig_f(gf)*cs + sig_f(gi)*tanh_f(gg);
    float hsn = sig_f(go)*tanh_f(csn);
    CS_n[(size_t)b*512 + h] = csn;
    HSb_n[(size_t)b*512 + h] = f2b(hsn);
    CSb_n[(size_t)b*512 + h] = f2b(csn);
  }
}

// ---------- DfA[(t*64+b), :] = [HSb[t][b] | CSb[t][b]] ----------
__global__ void k_dfa(const u16* __restrict__ HSb, const u16* __restrict__ CSb, u16* __restrict__ DfA) {
  int r = blockIdx.x; int t = r >> 6, b = r & 63;
  const uint2* hs = (const uint2*)(HSb + ((size_t)t*64 + b)*512);
  const uint2* cs = (const uint2*)(CSb + ((size_t)t*64 + b)*512);
  uint2* dst = (uint2*)(DfA + (size_t)r*1024);
  int tid = threadIdx.x;   // 256
  dst[tid] = (tid < 128) ? hs[tid] : cs[tid-128];
}

// ---------- attention + feat build, one block per (t,b) ----------
__global__ __launch_bounds__(256) void k_attn(
    const u16* __restrict__ G, const float* __restrict__ df,
    const float* __restrict__ we_w, const u16* __restrict__ Enc16,
    const u16* __restrict__ HSb, u16* __restrict__ Feat)
{
  int r = blockIdx.x, t = r>>6, b = r&63;
  int tid = threadIdx.x;
  __shared__ float weS[1024];
  __shared__ float eP[2][128];
  __shared__ float aS[128];
  __shared__ float redM, redS;
  for (int i=tid;i<1024;i+=256) weS[i] = we_w[i];
  __syncthreads();
  int s = tid & 127, cg = tid >> 7;
  const u16* Gb = G + (size_t)b*131072;
  const float* dfr = df + (size_t)r*1024;
  float p = 0.f;
  #pragma unroll 8
  for (int c = cg*512; c < cg*512 + 512; ++c) {
    float x = b2f(Gb[(size_t)c*128 + s]) + dfr[((c&7)<<7) + s];
    p += weS[c]*tanh_f(x);
  }
  eP[cg][s] = p;
  __syncthreads();
  if (tid < 128) aS[tid] = eP[0][tid] + eP[1][tid];
  __syncthreads();
  if (tid < 64) {
    float m = fmaxf(aS[tid], aS[tid+64]);
    #pragma unroll
    for (int off=32; off; off>>=1) m = fmaxf(m, __shfl_xor(m, off, 64));
    float sm = __expf(aS[tid]-m) + __expf(aS[tid+64]-m);
    #pragma unroll
    for (int off=32; off; off>>=1) sm += __shfl_xor(sm, off, 64);
    if (tid==0){ redM = m; redS = sm; }
  }
  __syncthreads();
  if (tid < 128) aS[tid] = __expf(aS[tid]-redM)/redS;
  __syncthreads();
  const u16* encb = Enc16 + (size_t)b*131072;
  u16* Fr = Feat + (size_t)r*1536;
  int h4 = tid*4;
  float a0=0,a1=0,a2=0,a3=0;
  for (int s2=0;s2<128;++s2) {
    float av = aS[s2];
    u16x4 v = *(const u16x4*)(encb + (size_t)s2*1024 + h4);
    a0 += av*b2f(v.x); a1 += av*b2f(v.y); a2 += av*b2f(v.z); a3 += av*b2f(v.w);
  }
  u16x4 o; o.x = f2b(a0); o.y = f2b(a1); o.z = f2b(a2); o.w = f2b(a3);
  *(u16x4*)(Fr + h4) = o;
  const u16* hsn = HSb + ((size_t)(t+1)*64 + b)*512;
  if (tid < 128) *(u16x4*)(Fr + 1024 + tid*4) = *(const u16x4*)(hsn + tid*4);
}

// ---------- in-place log_softmax over each 32000-wide fp32 row ----------
__global__ __launch_bounds__(256) void k_lsm(float* __restrict__ out) {
  int r = blockIdx.x;
  float* row = out + (size_t)r*32000;
  int tid = threadIdx.x, wid = tid>>6;
  __shared__ float redA[4], redB[4];
  float m = -3.0e38f;
  for (int i = tid*4; i < 32000; i += 1024) {
    float4 v = *(const float4*)(row + i);
    m = fmaxf(m, fmaxf(fmaxf(v.x, v.y), fmaxf(v.z, v.w)));
  }
  #pragma unroll
  for (int off=32; off; off>>=1) m = fmaxf(m, __shfl_xor(m, off, 64));
  if ((tid&63)==0) redA[wid] = m;
  __syncthreads();
  m = fmaxf(fmaxf(redA[0],redA[1]), fmaxf(redA[2],redA[3]));
  float sacc = 0.f;
  for (int i = tid*4; i < 32000; i += 1024) {
    float4 v = *(const float4*)(row + i);
    sacc += __expf(v.x-m) + __expf(v.y-m) + __expf(v.z-m) + __expf(v.w-m);
  }
  #pragma unroll
  for (int off=32; off; off>>=1) sacc += __shfl_xor(sacc, off, 64);
  if ((tid&63)==0) redB[wid] = sacc;
  __syncthreads();
  float lse = m + logf(redB[0]+redB[1]+redB[2]+redB[3]);
  for (int i = tid*4; i < 32000; i += 1024) {
    float4 v = *(const float4*)(row + i);
    v.x -= lse; v.y -= lse; v.z -= lse; v.w -= lse;
    *(float4*)(row + i) = v;
  }
}

extern "C" void kernel_launch(void* const* d_in, const int* in_sizes, int n_in,
                              void* d_out, int out_size, void* d_ws, size_t ws_size,
                              hipStream_t stream) {
  (void)in_sizes; (void)n_in; (void)out_size;
  const float* enc    = (const float*)d_in[0];
  const float* hs0    = (const float*)d_in[1];
  const float* cs0    = (const float*)d_in[2];
  const float* target = (const float*)d_in[3];
  const float* wh_w   = (const float*)d_in[4];
  const float* ws_w   = (const float*)d_in[5];
  const float* ws_b   = (const float*)d_in[6];
  const float* we_w   = (const float*)d_in[7];
  const float* W_ih   = (const float*)d_in[8];
  const float* W_hh   = (const float*)d_in[9];
  const float* b_ih   = (const float*)d_in[10];
  const float* b_hh   = (const float*)d_in[11];
  const float* Vp_w   = (const float*)d_in[12];
  const float* Vp_b   = (const float*)d_in[13];
  float* out = (float*)d_out;

  char* ws = (char*)d_ws;
  u16*   X2    = (u16*)  (ws + 0);           //  2 MB
  u16*   EBt   = (u16*)  (ws + 2097152);     // 16 MB
  u16*   G     = (u16*)  (ws + 18874368);    // 16 MB
  float* Xg    = (float*)(ws + 35651584);    // 16 MB (dead after LSTM)
  u16*   Enc16 = (u16*)  (ws + 35651584);    // 16 MB, aliases Xg (written after LSTM)
  u16*   HSb   = (u16*)  (ws + 52428800);    //  2.1 MB: 33x64x512
  u16*   CSb   = (u16*)  (ws + 54591488);
  float* CS    = (float*)(ws + 56754176);    //  4.3 MB
  u16*   DfA   = (u16*)  (ws + 61079552);    //  4 MB
  float* dfb   = (float*)(ws + 65273856);    //  8 MB
  u16*   Feat  = (u16*)  (ws + 73662464);    //  6 MB
  u16*   Wih16 = (u16*)  (ws + 79953920);    //  2 MB
  u16*   Whw16 = (u16*)  (ws + 82051072);
  u16*   Wsw16 = (u16*)  (ws + 84148224);
  u16*   Whh16 = (u16*)  (ws + 86245376);
  u16*   Vpw16 = (u16*)  (ws + 88342528);    // 98.3 MB, tier A only
  const bool tierA = ws_size >= (size_t)88342528 + 98304000;

  // weight conversions (each 1,048,576 elems -> 262,144 float4)
  k_cvt<<<1024, 256, 0, stream>>>(W_ih, Wih16, 262144);
  k_cvt<<<1024, 256, 0, stream>>>(wh_w, Whw16, 262144);
  k_cvt<<<1024, 256, 0, stream>>>(ws_w, Wsw16, 262144);
  k_cvt<<<1024, 256, 0, stream>>>(W_hh, Whh16, 262144);
  if (tierA) k_cvt<<<48000, 256, 0, stream>>>(Vp_w, Vpw16, 12288000);

  k_init<<<128, 256, 0, stream>>>(hs0, cs0, HSb, CSb, CS);
  k_x2<<<2048, 128, 0, stream>>>(target, X2);
  k_ebt<<<dim3(16,2,64), 256, 0, stream>>>(enc, EBt);

  // Xg = X2 @ W_ih^T + b_ih + b_hh   (M=2048, N=2048, K=512) -> f32
  gemm_bt<<<dim3(16,16,1), 256, 0, stream>>>(X2, Wih16, Xg, b_ih, b_hh,
      2048, 2048, 512, 512, 512, 2048, 0, 0, 0, 0, 0);
  // G[b] = wh_w @ EBt[b]^T   (M=1024, N=128, K=1024, batch=64) -> bf16
  gemm_bt<<<dim3(1,8,64), 256, 0, stream>>>(Whw16, EBt, G, nullptr, nullptr,
      1024, 128, 1024, 1024, 1024, 128, 0, 131072, 131072, 1, 0);

  for (int t = 0; t < 32; ++t)
    lstm_step<<<32, 256, 0, stream>>>(HSb + (size_t)t*32768, CS + (size_t)t*32768, Whh16,
                                      Xg + (size_t)t*64*2048,
                                      HSb + (size_t)(t+1)*32768, CS + (size_t)(t+1)*32768,
                                      CSb + (size_t)(t+1)*32768);

  // Enc16[b][s][h] = bf16(enc[b][s][h])  (aliases Xg; Xg dead now)
  k_cvt<<<8192, 256, 0, stream>>>(enc, Enc16, 2097152);

  k_dfa<<<2048, 256, 0, stream>>>(HSb, CSb, DfA);
  // df = DfA @ ws_w^T + ws_b   (M=2048, N=1024, K=1024) -> f32
  gemm_bt<<<dim3(8,16,1), 256, 0, stream>>>(DfA, Wsw16, dfb, ws_b, nullptr,
      2048, 1024, 1024, 1024, 1024, 1024, 0, 0, 0, 0, 0);
  k_attn<<<2048, 256, 0, stream>>>(G, dfb, we_w, Enc16, HSb, Feat);

  // logits = Feat @ Vp_w^T + Vp_b  (M=2048, N=32000, K=1536) -> f32 d_out
  // nwg = 250*16 = 4000, divisible by 8 -> XCD-chunked swizzle is bijective.
  if (tierA)
    gemm_bt<<<dim3(250,16,1), 256, 0, stream>>>(Feat, Vpw16, out, Vp_b, nullptr,
        2048, 32000, 1536, 1536, 1536, 32000, 0, 0, 0, 0, 1);
  else
    gemm_a16b32<<<dim3(250,16,1), 256, 0, stream>>>(Feat, Vp_w, out, Vp_b,
        2048, 32000, 1536, 1536, 1536, 32000, 1);

  k_lsm<<<2048, 256, 0, stream>>>(out);
}

// Round 2
// 1468.762 us; speedup vs baseline: 1.0401x; 1.0220x over previous
//
#include <hip/hip_runtime.h>
#include <hip/hip_bf16.h>
#include <cstdint>
#include <cstddef>

// Sizes: B=64, S=128, T=32, H=512, E=512, VOC=32000, A=2H=1024. All I/O fp32.
typedef unsigned short u16;
typedef __attribute__((ext_vector_type(8))) short s16x8;   // 8 bf16 (MFMA A/B frag)
typedef __attribute__((ext_vector_type(4))) float f32x4;   // MFMA acc
typedef __attribute__((ext_vector_type(4))) unsigned short u16x4;

__device__ __forceinline__ float b2f(u16 u){ unsigned int i = ((unsigned int)u)<<16; float f; __builtin_memcpy(&f,&i,4); return f; }
__device__ __forceinline__ u16 f2b(float f){ unsigned int i; __builtin_memcpy(&i,&f,4); i = (i + 0x7fffu + ((i>>16)&1u))>>16; return (u16)i; }
__device__ __forceinline__ float tanh_f(float x){ return 1.f - 2.f/(1.f + __expf(2.f*x)); } // inf-safe
__device__ __forceinline__ float sig_f(float x){ return 1.f/(1.f + __expf(-x)); }

__device__ __forceinline__ void cp16(const u16* g, u16* l) {
  // async global->LDS: LDS dest = wave-uniform base + lane*16B
  __builtin_amdgcn_global_load_lds((const __attribute__((address_space(1))) unsigned int*)g,
                                   (__attribute__((address_space(3))) unsigned int*)l, 16, 0, 0);
}

// ---------- fp32 -> bf16 bulk convert (n4 = n/4 float4 groups) ----------
__global__ void k_cvt(const float* __restrict__ src, u16* __restrict__ dst, int n4) {
  int i = blockIdx.x*256 + threadIdx.x;
  if (i >= n4) return;
  float4 v = ((const float4*)src)[i];
  u16x4 o; o.x = f2b(v.x); o.y = f2b(v.y); o.z = f2b(v.z); o.w = f2b(v.w);
  ((u16x4*)dst)[i] = o;
}

// ============================================================================
// 256x256-tile 8-phase-style GEMM: C = A(M,K) @ B(N,K)^T + bias, bf16 in, f32 out.
// 512 threads = 8 waves (2M x 4N). BK=32 K-tiles, 4-deep LDS ring (128 KiB),
// staged 3 tiles ahead with counted vmcnt (never 0 in main loop). T2 swizzle,
// T5 setprio, XCD-chunked block swizzle. Requires M%256==0, N%256==0, K%32==0,
// K>=96, (grid.x*grid.y)%8==0.
// ============================================================================
__global__ __launch_bounds__(512, 1) void gemm256_bt(
    const u16* __restrict__ A, const u16* __restrict__ B, float* __restrict__ C,
    const float* __restrict__ bias, int M, int N, int K, int ldA, int ldB, int ldC)
{
  (void)M; (void)N;
  __shared__ u16 As[4*8192];   // 4 bufs x 256x32 bf16 = 64 KiB
  __shared__ u16 Bs[4*8192];   // 64 KiB

  // XCD-chunked swizzle, M-innermost within chunk
  {
  }
  const int nx = gridDim.x, ny = gridDim.y;
  const int nwg = nx*ny;
  const int orig = blockIdx.y*nx + blockIdx.x;
  const int cpx = nwg >> 3;
  const int id = (orig & 7)*cpx + (orig >> 3);
  const int byy = id % ny;
  const int bxx = id / ny;
  const int tn = bxx*256, tm = byy*256;

  const int tid = threadIdx.x, wid = tid>>6, lane = tid&63;
  const int wm = wid & 1, wn = wid >> 1;   // wave -> (2 M) x (4 N)
  const int lr = lane & 15, ks = lane >> 4;
  const int NT = K >> 5;                   // number of 32-wide K-tiles

  f32x4 acc[8][4];
  #pragma unroll
  for (int m=0;m<8;++m)
    #pragma unroll
    for (int n=0;n<4;++n) acc[m][n] = (f32x4){0.f,0.f,0.f,0.f};

  // --- staging: per wave, half h covers rows h*128 + wid*16 .. +15 (1 KiB) ---
  // linear LDS byte d = (wid*64+lane)*16 + h*8192 -> row r = d>>6, slot = (d>>4)&3.
  // swizzle (involution): logical slot = slot ^ ((r>>1)&3). gload_lds writes
  // linearly, so the GLOBAL source is pre-swizzled; ds_read applies the XOR.
  const int st_r0 = wid*16 + (lane>>2);        // row within half (h=0)
  const int st_sl0 = (lane&3) ^ ((st_r0>>1)&3);
  const int st_r1 = 128 + st_r0;
  const int st_sl1 = (lane&3) ^ ((st_r1>>1)&3);

  #define STAGE_A(kt_) do { \
    u16* dst = As + (((kt_)&3)<<13) + (wid<<9); \
    cp16(A + (size_t)(tm + st_r0)*ldA + (kt_)*32 + st_sl0*8, dst); \
    cp16(A + (size_t)(tm + st_r1)*ldA + (kt_)*32 + st_sl1*8, dst + 4096); \
  } while(0)
  #define STAGE_B(kt_) do { \
    u16* dst = Bs + (((kt_)&3)<<13) + (wid<<9); \
    cp16(B + (size_t)(tn + st_r0)*ldB + (kt_)*32 + st_sl0*8, dst); \
    cp16(B + (size_t)(tn + st_r1)*ldB + (kt_)*32 + st_sl1*8, dst + 4096); \
  } while(0)

  // prologue: stage tiles 0,1,2 (12 loads/wave); gate tile 0 (keep 8 in flight)
  {
    int pmax = NT < 3 ? NT : 3;
    for (int j=0;j<pmax;++j) { STAGE_A(j); STAGE_B(j); }
  }
  asm volatile("s_waitcnt vmcnt(8)" ::: "memory");
  __builtin_amdgcn_s_barrier();

  for (int kt = 0; kt < NT; ++kt) {
    const u16* Ap = As + ((kt&3)<<13);
    const u16* Bp = Bs + ((kt&3)<<13);
    const bool st = (kt + 3) < NT;

    // ---------- phase A: frags b0..b3, a0..a3; MFMA m0..3 ----------
    s16x8 bf[4], af[4];
    #pragma unroll
    for (int n=0;n<4;++n) {
      int rb = wn*64 + n*16 + lr;
      bf[n] = *(const s16x8*)(Bp + rb*32 + ((ks ^ ((rb>>1)&3))<<3));
    }
    #pragma unroll
    for (int m=0;m<4;++m) {
      int ra = wm*128 + m*16 + lr;
      af[m] = *(const s16x8*)(Ap + ra*32 + ((ks ^ ((ra>>1)&3))<<3));
    }
    if (st) STAGE_A(kt+3);
    __builtin_amdgcn_s_barrier();
    __builtin_amdgcn_s_setprio(1);
    #pragma unroll
    for (int m=0;m<4;++m)
      #pragma unroll
      for (int n=0;n<4;++n)
        acc[m][n] = __builtin_amdgcn_mfma_f32_16x16x32_bf16(af[m], bf[n], acc[m][n], 0,0,0);
    __builtin_amdgcn_s_setprio(0);
    __builtin_amdgcn_s_barrier();

    // ---------- phase B: frags a4..a7; MFMA m4..7 ----------
    s16x8 ag[4];
    #pragma unroll
    for (int m=0;m<4;++m) {
      int ra = wm*128 + (m+4)*16 + lr;
      ag[m] = *(const s16x8*)(Ap + ra*32 + ((ks ^ ((ra>>1)&3))<<3));
    }
    if (st) STAGE_B(kt+3);
    __builtin_amdgcn_s_barrier();
    __builtin_amdgcn_s_setprio(1);
    #pragma unroll
    for (int m=0;m<4;++m)
      #pragma unroll
      for (int n=0;n<4;++n)
        acc[m+4][n] = __builtin_amdgcn_mfma_f32_16x16x32_bf16(ag[m], bf[n], acc[m+4][n], 0,0,0);
    __builtin_amdgcn_s_setprio(0);
    // gate tile kt+1 (counted, never 0 until tail): outstanding tiles kt+1..min(kt+3,NT-1)
    {
      int lastStaged = (kt+3 < NT) ? (kt+3) : (NT-1);
      int cnt = lastStaged - kt;
      if (cnt == 3)      asm volatile("s_waitcnt vmcnt(8)" ::: "memory");
      else if (cnt == 2) asm volatile("s_waitcnt vmcnt(4)" ::: "memory");
      else if (cnt == 1) asm volatile("s_waitcnt vmcnt(0)" ::: "memory");
    }
    __builtin_amdgcn_s_barrier();
  }
  #undef STAGE_A
  #undef STAGE_B

  // ---------- epilogue ----------
  #pragma unroll
  for (int m=0;m<8;++m) {
    #pragma unroll
    for (int n=0;n<4;++n) {
      int col = tn + wn*64 + n*16 + lr;
      float badd = bias ? bias[col] : 0.f;
      #pragma unroll
      for (int r=0;r<4;++r) {
        int row = tm + wm*128 + m*16 + ks*4 + r;
        C[(size_t)row*ldC + col] = acc[m][n][r] + badd;
      }
    }
  }
}

// ---------- C = A(M,K) @ B(N,K)^T (+bias1+bias2), bf16 in, f32/bf16 out ----------
// grid: (N/128, M/128, batch), 256 threads. M,N mult of 128; K mult of 32.
__global__ __launch_bounds__(256, 2) void gemm_bt(
    const u16* __restrict__ A, const u16* __restrict__ B, void* __restrict__ Cv,
    const float* __restrict__ bias1, const float* __restrict__ bias2,
    int M, int N, int K, int ldA, int ldB, int ldC,
    long long strideA, long long strideB, long long strideC, int outBf16, int swz)
{
  __shared__ u16 As[128*32];
  __shared__ u16 Bs[128*32];
  const int bz = blockIdx.z;
  const u16* Ab = A + (size_t)bz*strideA;
  const u16* Bb = B + (size_t)bz*strideB;
  int bxx = blockIdx.x, byy = blockIdx.y;
  if (swz) {
    int nx = gridDim.x, ny = gridDim.y;
    int nwg = nx * ny;
    int orig = byy * nx + bxx;
    int cpx = nwg >> 3;
    int id = (orig & 7) * cpx + (orig >> 3);
    byy = id % ny;
    bxx = id / ny;
  }
  const int tn = bxx * 128;
  const int tm = byy * 128;
  const int tid = threadIdx.x, wid = tid>>6, lane = tid&63;
  const int wm = wid & 1, wn = wid >> 1;
  const int lrow = lane & 15, lk = (lane>>4)*8;

  f32x4 acc[4][4];
  #pragma unroll
  for (int i=0;i<4;++i)
    #pragma unroll
    for (int j=0;j<4;++j) acc[i][j] = (f32x4){0.f,0.f,0.f,0.f};

  const int srow = lane>>2;
  const int scol = (lane&3)*8;

  for (int k0 = 0; k0 < K; k0 += 32) {
    int c0 = wid, c1 = wid + 4;
    cp16(Ab + (size_t)(tm + c0*16 + srow)*ldA + k0 + scol, As + c0*512);
    cp16(Ab + (size_t)(tm + c1*16 + srow)*ldA + k0 + scol, As + c1*512);
    cp16(Bb + (size_t)(tn + c0*16 + srow)*ldB + k0 + scol, Bs + c0*512);
    cp16(Bb + (size_t)(tn + c1*16 + srow)*ldB + k0 + scol, Bs + c1*512);
    __syncthreads();

    s16x8 af[4], bfr[4];
    #pragma unroll
    for (int mt=0; mt<4; ++mt)
      af[mt] = *(const s16x8*)(As + (size_t)(wm*64 + mt*16 + lrow)*32 + lk);
    #pragma unroll
    for (int nt=0; nt<4; ++nt)
      bfr[nt] = *(const s16x8*)(Bs + (size_t)(wn*64 + nt*16 + lrow)*32 + lk);
    #pragma unroll
    for (int mt=0; mt<4; ++mt)
      #pragma unroll
      for (int nt=0; nt<4; ++nt)
        acc[mt][nt] = __builtin_amdgcn_mfma_f32_16x16x32_bf16(af[mt], bfr[nt], acc[mt][nt], 0,0,0);
    __syncthreads();
  }

  float* Cf = (float*)Cv + (size_t)bz*strideC;
  u16*   Ch = (u16*)Cv + (size_t)bz*strideC;
  #pragma unroll
  for (int mt=0; mt<4; ++mt) {
    #pragma unroll
    for (int nt=0; nt<4; ++nt) {
      int col = tn + wn*64 + nt*16 + (lane&15);
      float badd = 0.f;
      if (bias1) badd += bias1[col];
      if (bias2) badd += bias2[col];
      #pragma unroll
      for (int r=0; r<4; ++r) {
        int row = tm + wm*64 + mt*16 + (lane>>4)*4 + r;
        float v = acc[mt][nt][r] + badd;
        if (outBf16) Ch[(size_t)row*ldC + col] = f2b(v);
        else         Cf[(size_t)row*ldC + col] = v;
      }
    }
  }
}

// ---------- vocab GEMM variant (tier B): A bf16 (cp16), B fp32 inline-converted ----------
__global__ __launch_bounds__(256, 2) void gemm_a16b32(
    const u16* __restrict__ A, const float* __restrict__ B, float* __restrict__ C,
    const float* __restrict__ bias, int M, int N, int K, int ldA, int ldB, int ldC, int swz)
{
  __shared__ u16 As[128*32];
  __shared__ u16 Bs[128*32];
  int bxx = blockIdx.x, byy = blockIdx.y;
  if (swz) {
    int nx = gridDim.x, ny = gridDim.y;
    int nwg = nx * ny;
    int orig = byy * nx + bxx;
    int cpx = nwg >> 3;
    int id = (orig & 7) * cpx + (orig >> 3);
    byy = id % ny;
    bxx = id / ny;
  }
  const int tn = bxx * 128;
  const int tm = byy * 128;
  const int tid = threadIdx.x, wid = tid>>6, lane = tid&63;
  const int wm = wid & 1, wn = wid >> 1;
  const int lrow = lane & 15, lk = (lane>>4)*8;

  f32x4 acc[4][4];
  #pragma unroll
  for (int i=0;i<4;++i)
    #pragma unroll
    for (int j=0;j<4;++j) acc[i][j] = (f32x4){0.f,0.f,0.f,0.f};

  const int srow = lane>>2;
  const int scol = (lane&3)*8;
  const int brow0 = tid>>3;        // 0..31
  const int bcol  = (tid&7)*4;     // 0..28

  for (int k0 = 0; k0 < K; k0 += 32) {
    int c0 = wid, c1 = wid + 4;
    cp16(A + (size_t)(tm + c0*16 + srow)*ldA + k0 + scol, As + c0*512);
    cp16(A + (size_t)(tm + c1*16 + srow)*ldA + k0 + scol, As + c1*512);
    #pragma unroll
    for (int rr=0; rr<4; ++rr) {
      int row = rr*32 + brow0;
      float4 v = *(const float4*)(B + (size_t)(tn + row)*ldB + k0 + bcol);
      u16x4 o; o.x = f2b(v.x); o.y = f2b(v.y); o.z = f2b(v.z); o.w = f2b(v.w);
      *(u16x4*)(Bs + (size_t)row*32 + bcol) = o;
    }
    __syncthreads();

    s16x8 af[4], bfr[4];
    #pragma unroll
    for (int mt=0; mt<4; ++mt)
      af[mt] = *(const s16x8*)(As + (size_t)(wm*64 + mt*16 + lrow)*32 + lk);
    #pragma unroll
    for (int nt=0; nt<4; ++nt)
      bfr[nt] = *(const s16x8*)(Bs + (size_t)(wn*64 + nt*16 + lrow)*32 + lk);
    #pragma unroll
    for (int mt=0; mt<4; ++mt)
      #pragma unroll
      for (int nt=0; nt<4; ++nt)
        acc[mt][nt] = __builtin_amdgcn_mfma_f32_16x16x32_bf16(af[mt], bfr[nt], acc[mt][nt], 0,0,0);
    __syncthreads();
  }

  #pragma unroll
  for (int mt=0; mt<4; ++mt) {
    #pragma unroll
    for (int nt=0; nt<4; ++nt) {
      int col = tn + wn*64 + nt*16 + (lane&15);
      float badd = bias ? bias[col] : 0.f;
      #pragma unroll
      for (int r=0; r<4; ++r) {
        int row = tm + wm*64 + mt*16 + (lane>>4)*4 + r;
        C[(size_t)row*ldC + col] = acc[mt][nt][r] + badd;
      }
    }
  }
}

// ---------- init: HSb[0]=bf16(hs0), CSb[0]=bf16(cs0), CS[0]=cs0 ----------
__global__ void k_init(const float* __restrict__ hs0, const float* __restrict__ cs0,
                       u16* __restrict__ HSb0, u16* __restrict__ CSb0, float* __restrict__ CS0) {
  int i = blockIdx.x*256 + threadIdx.x;   // 32768 total
  HSb0[i] = f2b(hs0[i]);
  float c = cs0[i];
  CSb0[i] = f2b(c);
  CS0[i] = c;
}

// ---------- X2[(t*64+b), e] = bf16(target[b, t, e]) ----------
__global__ void k_x2(const float* __restrict__ target, u16* __restrict__ X2) {
  int r = blockIdx.x;               // 0..2047
  int t = r >> 6, b = r & 63;
  float4 v = ((const float4*)(target + ((size_t)b*32 + t)*512))[threadIdx.x]; // 128 thr
  u16x4 o; o.x = f2b(v.x); o.y = f2b(v.y); o.z = f2b(v.z); o.w = f2b(v.w);
  *(u16x4*)(X2 + (size_t)r*512 + threadIdx.x*4) = o;
}

// ---------- EBt[b][s][c] = bf16(enc_flat[b][c*128 + s]) ----------
__global__ void k_ebt(const float* __restrict__ enc, u16* __restrict__ EBt) {
  __shared__ u16 tile[64][72];
  int b = blockIdx.z;
  int c0 = blockIdx.x*64, s0 = blockIdx.y*64;
  int tid = threadIdx.x;
  int j = tid & 63, i0 = tid >> 6;
  const float* src = enc + (size_t)b*131072;
  for (int i = i0; i < 64; i += 4)
    tile[i][j] = f2b(src[(size_t)(c0+i)*128 + (s0+j)]);
  __syncthreads();
  u16* dst = EBt + (size_t)b*131072;
  for (int i = i0; i < 64; i += 4)
    dst[(size_t)(s0+i)*1024 + (c0+j)] = tile[j][i];
}

// ---------- one LSTM step ----------
__global__ __launch_bounds__(256, 1) void lstm_step(
    const u16* __restrict__ HSb_t, const float* __restrict__ CS_t,
    const u16* __restrict__ Whh, const float* __restrict__ Xg_t,
    u16* __restrict__ HSb_n, float* __restrict__ CS_n, u16* __restrict__ CSb_n)
{
  int tid = threadIdx.x, wid = tid>>6, lane = tid&63;
  int hc = blockIdx.x * 16;
  int lr = lane & 15, lk = (lane>>4)*8;
  f32x4 acc[4];
  #pragma unroll
  for (int q=0;q<4;++q) acc[q] = (f32x4){0.f,0.f,0.f,0.f};
  int brow = wid*16 + lr;
  #pragma unroll
  for (int k0 = 0; k0 < 512; k0 += 32) {
    s16x8 a = *(const s16x8*)(HSb_t + (size_t)brow*512 + k0 + lk);
    #pragma unroll
    for (int q=0;q<4;++q) {
      int gj = q*512 + hc + lr;
      s16x8 bb = *(const s16x8*)(Whh + (size_t)gj*512 + k0 + lk);
      acc[q] = __builtin_amdgcn_mfma_f32_16x16x32_bf16(a, bb, acc[q], 0,0,0);
    }
  }
  int h = hc + lr;
  #pragma unroll
  for (int r=0;r<4;++r) {
    int b = wid*16 + (lane>>4)*4 + r;
    float gi = acc[0][r] + Xg_t[(size_t)b*2048 + h];
    float gf = acc[1][r] + Xg_t[(size_t)b*2048 + 512 + h];
    float gg = acc[2][r] + Xg_t[(size_t)b*2048 + 1024 + h];
    float go = acc[3][r] + Xg_t[(size_t)b*2048 + 1536 + h];
    float cs = CS_t[(size_t)b*512 + h];
    float csn = sig_f(gf)*cs + sig_f(gi)*tanh_f(gg);
    float hsn = sig_f(go)*tanh_f(csn);
    CS_n[(size_t)b*512 + h] = csn;
    HSb_n[(size_t)b*512 + h] = f2b(hsn);
    CSb_n[(size_t)b*512 + h] = f2b(csn);
  }
}

// ---------- DfA[(t*64+b), :] = [HSb[t][b] | CSb[t][b]] ----------
__global__ void k_dfa(const u16* __restrict__ HSb, const u16* __restrict__ CSb, u16* __restrict__ DfA) {
  int r = blockIdx.x; int t = r >> 6, b = r & 63;
  const uint2* hs = (const uint2*)(HSb + ((size_t)t*64 + b)*512);
  const uint2* cs = (const uint2*)(CSb + ((size_t)t*64 + b)*512);
  uint2* dst = (uint2*)(DfA + (size_t)r*1024);
  int tid = threadIdx.x;   // 256
  dst[tid] = (tid < 128) ? hs[tid] : cs[tid-128];
}

// ---------- attention + feat build, one block per (t,b) ----------
__global__ __launch_bounds__(256) void k_attn(
    const u16* __restrict__ G, const float* __restrict__ df,
    const float* __restrict__ we_w, const u16* __restrict__ Enc16,
    const u16* __restrict__ HSb, u16* __restrict__ Feat)
{
  int r = blockIdx.x, t = r>>6, b = r&63;
  int tid = threadIdx.x;
  __shared__ float weS[1024];
  __shared__ float eP[2][128];
  __shared__ float aS[128];
  __shared__ float redM, redS;
  for (int i=tid;i<1024;i+=256) weS[i] = we_w[i];
  __syncthreads();
  int s = tid & 127, cg = tid >> 7;
  const u16* Gb = G + (size_t)b*131072;
  const float* dfr = df + (size_t)r*1024;
  float p = 0.f;
  #pragma unroll 8
  for (int c = cg*512; c < cg*512 + 512; ++c) {
    float x = b2f(Gb[(size_t)c*128 + s]) + dfr[((c&7)<<7) + s];
    p += weS[c]*tanh_f(x);
  }
  eP[cg][s] = p;
  __syncthreads();
  if (tid < 128) aS[tid] = eP[0][tid] + eP[1][tid];
  __syncthreads();
  if (tid < 64) {
    float m = fmaxf(aS[tid], aS[tid+64]);
    #pragma unroll
    for (int off=32; off; off>>=1) m = fmaxf(m, __shfl_xor(m, off, 64));
    float sm = __expf(aS[tid]-m) + __expf(aS[tid+64]-m);
    #pragma unroll
    for (int off=32; off; off>>=1) sm += __shfl_xor(sm, off, 64);
    if (tid==0){ redM = m; redS = sm; }
  }
  __syncthreads();
  if (tid < 128) aS[tid] = __expf(aS[tid]-redM)/redS;
  __syncthreads();
  const u16* encb = Enc16 + (size_t)b*131072;
  u16* Fr = Feat + (size_t)r*1536;
  int h4 = tid*4;
  float a0=0,a1=0,a2=0,a3=0;
  for (int s2=0;s2<128;++s2) {
    float av = aS[s2];
    u16x4 v = *(const u16x4*)(encb + (size_t)s2*1024 + h4);
    a0 += av*b2f(v.x); a1 += av*b2f(v.y); a2 += av*b2f(v.z); a3 += av*b2f(v.w);
  }
  u16x4 o; o.x = f2b(a0); o.y = f2b(a1); o.z = f2b(a2); o.w = f2b(a3);
  *(u16x4*)(Fr + h4) = o;
  const u16* hsn = HSb + ((size_t)(t+1)*64 + b)*512;
  if (tid < 128) *(u16x4*)(Fr + 1024 + tid*4) = *(const u16x4*)(hsn + tid*4);
}

// ---------- in-place log_softmax over each 32000-wide fp32 row ----------
__global__ __launch_bounds__(256) void k_lsm(float* __restrict__ out) {
  int r = blockIdx.x;
  float* row = out + (size_t)r*32000;
  int tid = threadIdx.x, wid = tid>>6;
  __shared__ float redA[4], redB[4];
  float m = -3.0e38f;
  for (int i = tid*4; i < 32000; i += 1024) {
    float4 v = *(const float4*)(row + i);
    m = fmaxf(m, fmaxf(fmaxf(v.x, v.y), fmaxf(v.z, v.w)));
  }
  #pragma unroll
  for (int off=32; off; off>>=1) m = fmaxf(m, __shfl_xor(m, off, 64));
  if ((tid&63)==0) redA[wid] = m;
  __syncthreads();
  m = fmaxf(fmaxf(redA[0],redA[1]), fmaxf(redA[2],redA[3]));
  float sacc = 0.f;
  for (int i = tid*4; i < 32000; i += 1024) {
    float4 v = *(const float4*)(row + i);
    sacc += __expf(v.x-m) + __expf(v.y-m) + __expf(v.z-m) + __expf(v.w-m);
  }
  #pragma unroll
  for (int off=32; off; off>>=1) sacc += __shfl_xor(sacc, off, 64);
  if ((tid&63)==0) redB[wid] = sacc;
  __syncthreads();
  float lse = m + logf(redB[0]+redB[1]+redB[2]+redB[3]);
  for (int i = tid*4; i < 32000; i += 1024) {
    float4 v = *(const float4*)(row + i);
    v.x -= lse; v.y -= lse; v.z -= lse; v.w -= lse;
    *(float4*)(row + i) = v;
  }
}

extern "C" void kernel_launch(void* const* d_in, const int* in_sizes, int n_in,
                              void* d_out, int out_size, void* d_ws, size_t ws_size,
                              hipStream_t stream) {
  (void)in_sizes; (void)n_in; (void)out_size;
  const float* enc    = (const float*)d_in[0];
  const float* hs0    = (const float*)d_in[1];
  const float* cs0    = (const float*)d_in[2];
  const float* target = (const float*)d_in[3];
  const float* wh_w   = (const float*)d_in[4];
  const float* ws_w   = (const float*)d_in[5];
  const float* ws_b   = (const float*)d_in[6];
  const float* we_w   = (const float*)d_in[7];
  const float* W_ih   = (const float*)d_in[8];
  const float* W_hh   = (const float*)d_in[9];
  const float* b_ih   = (const float*)d_in[10];
  const float* b_hh   = (const float*)d_in[11];
  const float* Vp_w   = (const float*)d_in[12];
  const float* Vp_b   = (const float*)d_in[13];
  float* out = (float*)d_out;

  char* ws = (char*)d_ws;
  u16*   X2    = (u16*)  (ws + 0);           //  2 MB
  u16*   EBt   = (u16*)  (ws + 2097152);     // 16 MB
  u16*   G     = (u16*)  (ws + 18874368);    // 16 MB
  float* Xg    = (float*)(ws + 35651584);    // 16 MB (dead after LSTM)
  u16*   Enc16 = (u16*)  (ws + 35651584);    // 16 MB, aliases Xg (written after LSTM)
  u16*   HSb   = (u16*)  (ws + 52428800);    //  2.1 MB: 33x64x512
  u16*   CSb   = (u16*)  (ws + 54591488);
  float* CS    = (float*)(ws + 56754176);    //  4.3 MB
  u16*   DfA   = (u16*)  (ws + 61079552);    //  4 MB
  float* dfb   = (float*)(ws + 65273856);    //  8 MB
  u16*   Feat  = (u16*)  (ws + 73662464);    //  6 MB
  u16*   Wih16 = (u16*)  (ws + 79953920);    //  2 MB
  u16*   Whw16 = (u16*)  (ws + 82051072);
  u16*   Wsw16 = (u16*)  (ws + 84148224);
  u16*   Whh16 = (u16*)  (ws + 86245376);
  u16*   Vpw16 = (u16*)  (ws + 88342528);    // 98.3 MB, tier A only
  const bool tierA = ws_size >= (size_t)88342528 + 98304000;

  // weight conversions (each 1,048,576 elems -> 262,144 float4)
  k_cvt<<<1024, 256, 0, stream>>>(W_ih, Wih16, 262144);
  k_cvt<<<1024, 256, 0, stream>>>(wh_w, Whw16, 262144);
  k_cvt<<<1024, 256, 0, stream>>>(ws_w, Wsw16, 262144);
  k_cvt<<<1024, 256, 0, stream>>>(W_hh, Whh16, 262144);
  if (tierA) k_cvt<<<48000, 256, 0, stream>>>(Vp_w, Vpw16, 12288000);

  k_init<<<128, 256, 0, stream>>>(hs0, cs0, HSb, CSb, CS);
  k_x2<<<2048, 128, 0, stream>>>(target, X2);
  k_ebt<<<dim3(16,2,64), 256, 0, stream>>>(enc, EBt);

  // Xg = X2 @ W_ih^T + b_ih + b_hh   (M=2048, N=2048, K=512) -> f32
  gemm_bt<<<dim3(16,16,1), 256, 0, stream>>>(X2, Wih16, Xg, b_ih, b_hh,
      2048, 2048, 512, 512, 512, 2048, 0, 0, 0, 0, 0);
  // G[b] = wh_w @ EBt[b]^T   (M=1024, N=128, K=1024, batch=64) -> bf16
  gemm_bt<<<dim3(1,8,64), 256, 0, stream>>>(Whw16, EBt, G, nullptr, nullptr,
      1024, 128, 1024, 1024, 1024, 128, 0, 131072, 131072, 1, 0);

  for (int t = 0; t < 32; ++t)
    lstm_step<<<32, 256, 0, stream>>>(HSb + (size_t)t*32768, CS + (size_t)t*32768, Whh16,
                                      Xg + (size_t)t*64*2048,
                                      HSb + (size_t)(t+1)*32768, CS + (size_t)(t+1)*32768,
                                      CSb + (size_t)(t+1)*32768);

  // Enc16[b][s][h] = bf16(enc[b][s][h])  (aliases Xg; Xg dead now)
  k_cvt<<<8192, 256, 0, stream>>>(enc, Enc16, 2097152);

  k_dfa<<<2048, 256, 0, stream>>>(HSb, CSb, DfA);
  // df = DfA @ ws_w^T + ws_b   (M=2048, N=1024, K=1024) -> f32
  gemm_bt<<<dim3(8,16,1), 256, 0, stream>>>(DfA, Wsw16, dfb, ws_b, nullptr,
      2048, 1024, 1024, 1024, 1024, 1024, 0, 0, 0, 0, 0);
  k_attn<<<2048, 256, 0, stream>>>(G, dfb, we_w, Enc16, HSb, Feat);

  // logits = Feat @ Vp_w^T + Vp_b  (M=2048, N=32000, K=1536) -> f32 d_out
  // 256^2-tile 8-phase pipeline; grid 125x8 = 1000 blocks (1000%8==0 for XCD swizzle)
  if (tierA)
    gemm256_bt<<<dim3(125, 8, 1), 512, 0, stream>>>(Feat, Vpw16, out, Vp_b,
        2048, 32000, 1536, 1536, 1536, 32000);
  else
    gemm_a16b32<<<dim3(250,16,1), 256, 0, stream>>>(Feat, Vp_w, out, Vp_b,
        2048, 32000, 1536, 1536, 1536, 32000, 1);

  k_lsm<<<2048, 256, 0, stream>>>(out);
}